// Round 1
// baseline (375.403 us; speedup 1.0000x reference)
//
#include <hip/hip_runtime.h>
#include <math.h>

#define FILTER_LEN 1024
#define HOP 512
#define CUTOFF 513
#define NFRAMES 4095
#define TLEN 2097152
#define NBATCH 16
#define FPB 3            // frames per block (4095 = 3 * 1365, no ragged edge)
#define NTHREADS 192     // 3 waves, one wave per frame
#define GROUPS 1365
#define LDSZ 1088        // 1024 + 64 pad slots
#define LDX(e) ((e) + ((e) >> 4))   // +1 pad every 16 elements -> breaks pow2 write strides

__device__ __forceinline__ float2 cmul(float2 a, float2 b) {
    return make_float2(a.x * b.x - a.y * b.y, a.x * b.y + a.y * b.x);
}

__global__ __launch_bounds__(NTHREADS)
void stft_mag_kernel(const float* __restrict__ in, float* __restrict__ out) {
    __shared__ float2 buf[FPB][2][LDSZ];   // 52,224 B
    const int tid  = threadIdx.x;
    const int lane = tid & 63;
    const int f    = tid >> 6;             // wave index == frame slot
    const int g    = blockIdx.x;           // frame group within batch
    const int b    = blockIdx.y;           // batch
    const int n    = g * FPB + f;          // frame index, always < 4095

    // ---- load frame (1024 fp32, coalesced float4) into buf[f][0], imag = 0 ----
    const float4* src4 = (const float4*)(in + (size_t)b * TLEN + (size_t)n * HOP);
    #pragma unroll
    for (int i = 0; i < 4; ++i) {
        float4 v = src4[i * 64 + lane];
        int e = 4 * (i * 64 + lane);
        buf[f][0][LDX(e + 0)] = make_float2(v.x, 0.f);
        buf[f][0][LDX(e + 1)] = make_float2(v.y, 0.f);
        buf[f][0][LDX(e + 2)] = make_float2(v.z, 0.f);
        buf[f][0][LDX(e + 3)] = make_float2(v.w, 0.f);
    }
    __syncthreads();

    // ---- 5 radix-4 Stockham DIF stages (natural-order output, no bit reversal) ----
    // stage st: sub-FFT length n_t = 1024>>(2st), stride s = 1<<(2st), m = n_t/4.
    // butterfly idx in [0,256): p = idx>>2st, q = idx & (s-1); reads at idx + k*256
    // (since s*m == 256 for all stages), writes at q + s*(4p+k) = idx + 3sp + ks.
    #pragma unroll
    for (int st = 0; st < 5; ++st) {
        const float2* sb = buf[f][st & 1];
        float2*       db = buf[f][(st & 1) ^ 1];
        const int sh = 2 * st;
        const int s  = 1 << sh;
        #pragma unroll
        for (int u = 0; u < 4; ++u) {
            const int idx = lane + 64 * u;
            const int p   = idx >> sh;
            // ang = 2*pi * p / n_t = (2*pi/1024) * (idx & ~(s-1))
            const float ang = 6.283185307179586f * (1.0f / 1024.0f)
                              * (float)(idx & ~(s - 1));
            const float sn = __sinf(ang);
            const float cs = __cosf(ang);
            const float2 w1 = make_float2(cs, -sn);     // e^{-i*ang}
            const float2 w2 = cmul(w1, w1);
            const float2 w3 = cmul(w2, w1);

            const float2 a  = sb[LDX(idx)];
            const float2 bv = sb[LDX(idx + 256)];
            const float2 c  = sb[LDX(idx + 512)];
            const float2 d  = sb[LDX(idx + 768)];

            const float2 apc = make_float2(a.x + c.x,  a.y + c.y);
            const float2 amc = make_float2(a.x - c.x,  a.y - c.y);
            const float2 bpd = make_float2(bv.x + d.x, bv.y + d.y);
            const float2 bmd = make_float2(bv.x - d.x, bv.y - d.y);
            // jbmd = i*(b-d) = (-bmd.y, bmd.x)
            const float2 t1 = make_float2(amc.x + bmd.y, amc.y - bmd.x); // amc - jbmd
            const float2 t2 = make_float2(apc.x - bpd.x, apc.y - bpd.y);
            const float2 t3 = make_float2(amc.x - bmd.y, amc.y + bmd.x); // amc + jbmd

            const int wb = idx + 3 * s * p;
            db[LDX(wb)]         = make_float2(apc.x + bpd.x, apc.y + bpd.y);
            db[LDX(wb + s)]     = cmul(w1, t1);
            db[LDX(wb + 2 * s)] = cmul(w2, t2);
            db[LDX(wb + 3 * s)] = cmul(w3, t3);
        }
        __syncthreads();
    }

    // ---- magnitude of bins 0..512 -> out[b][c][n]; result sits in buf[f][1] ----
    const size_t ob = (size_t)b * ((size_t)CUTOFF * NFRAMES);
    for (int flat = tid; flat < CUTOFF * FPB; flat += NTHREADS) {
        const int cc = flat / 3;          // channel
        const int ff = flat - cc * 3;     // frame slot within block
        const float2 v = buf[ff][1][LDX(cc)];
        out[ob + (size_t)cc * NFRAMES + (size_t)(g * FPB + ff)] =
            sqrtf(v.x * v.x + v.y * v.y);
    }
}

extern "C" void kernel_launch(void* const* d_in, const int* in_sizes, int n_in,
                              void* d_out, int out_size, void* d_ws, size_t ws_size,
                              hipStream_t stream) {
    const float* in = (const float*)d_in[0];   // (16, 2097152) fp32
    // d_in[1] (forward_basis) unused: it is exactly the DFT matrix, computed here as FFT.
    float* out = (float*)d_out;                // (16, 513, 4095) fp32
    dim3 grid(GROUPS, NBATCH, 1);
    stft_mag_kernel<<<grid, NTHREADS, 0, stream>>>(in, out);
}

// Round 2
// 314.173 us; speedup vs baseline: 1.1949x; 1.1949x over previous
//
#include <hip/hip_runtime.h>
#include <math.h>

#define CUTOFF   513
#define NFRAMES  4095
#define TLEN     2097152
#define NBATCH   16
#define NW       4          // waves per block
#define ROUNDS   2          // FFT rounds per wave
#define PAIRS_PB 8          // pairs per block (= NW * ROUNDS), 16 frames/block

// drain this wave's outstanding LDS ops; compiler memory barrier.
// FFT phase is per-wave private, so no __syncthreads needed between stages.
#define WAVE_SYNC() asm volatile("s_waitcnt lgkmcnt(0)" ::: "memory")

// XOR bank swizzle in float2-element space: q = e ^ (b4? 0b0101 :0) ^ (b5? 0b1010 :0).
// Chosen so each stage's 16-lane access group (varying bits {0-3},{0,1,4,5},{2-5})
// maps injectively onto q mod 16 -> conflict-free for 8B/lane accesses.
__device__ __forceinline__ int SW(int e) {
    return e ^ (((e >> 4) & 1) * 5) ^ (((e >> 5) & 1) * 10);
}
// base-4 digit reversal of 10-bit index (5 digits)
__device__ __forceinline__ int dr4(int k) {
    return ((k & 3) << 8) | (((k >> 2) & 3) << 6) | (((k >> 4) & 3) << 4)
         | (((k >> 6) & 3) << 2) | ((k >> 8) & 3);
}
__device__ __forceinline__ float2 cmul(float2 a, float2 b) {
    return make_float2(a.x * b.x - a.y * b.y, a.x * b.y + a.y * b.x);
}

__global__ __launch_bounds__(256)
void stft_mag_kernel(const float* __restrict__ in, float* __restrict__ out) {
    __shared__ float2 fft[NW][1024];   // 32768 B, in-place DIF workspace (1 per wave)
    __shared__ float  mt[512 * 16];    // 32768 B, mag transpose tile; total = 64 KiB exactly
    const int tid  = threadIdx.x;
    const int lane = tid & 63;
    const int w    = tid >> 6;
    const int blk  = blockIdx.x;       // 0..255 (frame group)
    const int b    = blockIdx.y;       // batch
    const int n0   = 16 * blk;
    const float* bin  = in  + (size_t)b * TLEN;
    float*       bout = out + (size_t)b * ((size_t)CUTOFF * NFRAMES);

    for (int r = 0; r < ROUNDS; ++r) {
        const int  pl    = w + NW * r;            // pair slot in block, 0..7
        const int  p     = PAIRS_PB * blk + pl;   // pair in batch, 0..2047
        const bool noB   = (2 * p + 1) >= NFRAMES; // frame B (=4095) doesn't exist
        // ---- load pair: z[e] = frameA[e] + i*frameB[e]; frameB[e] = in[1024p+512+e]
        const float4* a4 = (const float4*)(bin + (size_t)1024 * p);
        #pragma unroll
        for (int i = 0; i < 4; ++i) {
            float4 rr = a4[lane + 64 * i];
            float4 ss = noB ? make_float4(0.f, 0.f, 0.f, 0.f) : a4[128 + lane + 64 * i];
            int e0 = 4 * (lane + 64 * i);
            fft[w][SW(e0 + 0)] = make_float2(rr.x, ss.x);
            fft[w][SW(e0 + 1)] = make_float2(rr.y, ss.y);
            fft[w][SW(e0 + 2)] = make_float2(rr.z, ss.z);
            fft[w][SW(e0 + 3)] = make_float2(rr.w, ss.w);
        }
        WAVE_SYNC();
        // ---- 5 in-place radix-4 DIF stages (output in base-4 digit-reversed order)
        #pragma unroll
        for (int t = 0; t < 5; ++t) {
            const int lgm = 8 - 2 * t;
            const int m   = 1 << lgm;
            #pragma unroll
            for (int u = 0; u < 4; ++u) {
                const int beta = lane + 64 * u;        // butterfly id, 0..255
                const int j    = beta & (m - 1);
                const int g    = beta >> lgm;
                const int i0   = (g << (lgm + 2)) + j; // g*4m + j
                // twiddle W_{4m}^j = e^{-i*2pi*(j*4^t)/1024}
                const float ang = (float)(j << (2 * t)) * 6.135923151542565e-03f;
                float sn, cs;
                __sincosf(ang, &sn, &cs);
                const float2 w1 = make_float2(cs, -sn);
                const float2 w2 = cmul(w1, w1);
                const float2 w3 = cmul(w2, w1);
                float2 a  = fft[w][SW(i0)];
                float2 bv = fft[w][SW(i0 + m)];
                float2 c  = fft[w][SW(i0 + 2 * m)];
                float2 d  = fft[w][SW(i0 + 3 * m)];
                float2 apc = make_float2(a.x + c.x,  a.y + c.y);
                float2 amc = make_float2(a.x - c.x,  a.y - c.y);
                float2 bpd = make_float2(bv.x + d.x, bv.y + d.y);
                float2 bmd = make_float2(bv.x - d.x, bv.y - d.y);
                float2 y1  = make_float2(amc.x + bmd.y, amc.y - bmd.x); // (a-c)-i(b-d)
                float2 y2  = make_float2(apc.x - bpd.x, apc.y - bpd.y);
                float2 y3  = make_float2(amc.x - bmd.y, amc.y + bmd.x); // (a-c)+i(b-d)
                fft[w][SW(i0)]         = make_float2(apc.x + bpd.x, apc.y + bpd.y);
                fft[w][SW(i0 + m)]     = cmul(w1, y1);
                fft[w][SW(i0 + 2 * m)] = cmul(w2, y2);
                fft[w][SW(i0 + 3 * m)] = cmul(w3, y3);
            }
            WAVE_SYNC();
        }
        // ---- Hermitian unpack + magnitude -> transpose tile. k = 8*lane + v.
        const int f0 = 2 * pl;
        #pragma unroll
        for (int v = 0; v < 8; ++v) {
            const int k  = 8 * lane + v;            // 0..511
            const int mk = (1024 - k) & 1023;
            float2 Zk = fft[w][SW(dr4(k))];
            float2 Zm = fft[w][SW(dr4(mk))];
            float ax = Zk.x + Zm.x, ay = Zk.y - Zm.y;   // 2*A_k
            float bx = Zk.x - Zm.x, by = Zk.y + Zm.y;   // 2*B_k (x -i, mag-invariant)
            float mA = 0.5f * sqrtf(ax * ax + ay * ay);
            float mB = 0.5f * sqrtf(bx * bx + by * by);
            mt[16 * k + ((f0     + (k >> 3)) & 15)] = mA;
            mt[16 * k + ((f0 + 1 + (k >> 3)) & 15)] = mB;
        }
        if (lane == 0) {   // bin 512: Z real/imag are A_512 / B_512; dr4(512)==2
            float2 Z = fft[w][SW(2)];
            bout[(size_t)512 * NFRAMES + (2 * p)] = fabsf(Z.x);
            if (!noB) bout[(size_t)512 * NFRAMES + (2 * p + 1)] = fabsf(Z.y);
        }
        WAVE_SYNC();   // readout reads fft[w] done before next round's load overwrites
    }
    __syncthreads();   // all waves' mt columns complete
    // ---- coalesced store: rows c=0..511, 16 frames per row = one 64B line each
    #pragma unroll 4
    for (int i = 0; i < 32; ++i) {
        int L = tid + 256 * i;
        int c = L >> 4, f = L & 15;
        int n = n0 + f;
        if (n < NFRAMES)
            bout[(size_t)c * NFRAMES + n] = mt[16 * c + ((f + (c >> 3)) & 15)];
    }
}

extern "C" void kernel_launch(void* const* d_in, const int* in_sizes, int n_in,
                              void* d_out, int out_size, void* d_ws, size_t ws_size,
                              hipStream_t stream) {
    const float* in = (const float*)d_in[0];   // (16, 2097152) fp32
    // d_in[1] (forward_basis) unused: it is exactly the DFT matrix; computed as FFT here.
    float* out = (float*)d_out;                // (16, 513, 4095) fp32
    dim3 grid(256, NBATCH, 1);
    stft_mag_kernel<<<grid, 256, 0, stream>>>(in, out);
}

// Round 3
// 311.968 us; speedup vs baseline: 1.2033x; 1.0071x over previous
//
#include <hip/hip_runtime.h>
#include <math.h>

#define CUTOFF   513
#define NFRAMES  4095
#define TLEN     2097152
#define NBATCH   16
#define NW       4   // waves per block; each wave: one packed pair-FFT (2 frames)

// compiler barrier + drain this wave's LDS ops (FFT phase is wave-private)
#define WAVE_SYNC() asm volatile("s_waitcnt lgkmcnt(0)" ::: "memory")

__device__ __forceinline__ float2 cadd(float2 a, float2 b){return make_float2(a.x+b.x, a.y+b.y);}
__device__ __forceinline__ float2 csub(float2 a, float2 b){return make_float2(a.x-b.x, a.y-b.y);}
__device__ __forceinline__ float2 cmul(float2 a, float2 b){return make_float2(a.x*b.x-a.y*b.y, a.x*b.y+a.y*b.x);}
__device__ __forceinline__ float2 cmul_mi(float2 a){return make_float2(a.y, -a.x);}  // *(-i)

// natural-order in/out 16-point DFT (W16 = e^{-2pi i/16}), fully in registers
__device__ __forceinline__ void fft16(float2* A) {
    const float C1 = 0.92387953251f, S1 = 0.38268343236f, HF = 0.70710678119f;
    float2 C[16];
    #pragma unroll
    for (int j4 = 0; j4 < 4; ++j4) {
        float2 a = A[j4], b = A[j4+4], c = A[j4+8], d = A[j4+12];
        float2 t0 = cadd(a,c), t1 = csub(a,c), t2 = cadd(b,d), t3 = csub(b,d);
        C[4*j4+0] = cadd(t0,t2);
        C[4*j4+1] = make_float2(t1.x + t3.y, t1.y - t3.x);   // t1 - i*t3
        C[4*j4+2] = csub(t0,t2);
        C[4*j4+3] = make_float2(t1.x - t3.y, t1.y + t3.x);   // t1 + i*t3
    }
    // twiddle C[j4][klo] *= W16^{j4*klo}
    C[4*1+1] = cmul(C[4*1+1], make_float2( C1,-S1));
    C[4*1+2] = cmul(C[4*1+2], make_float2( HF,-HF));
    C[4*1+3] = cmul(C[4*1+3], make_float2( S1,-C1));
    C[4*2+1] = cmul(C[4*2+1], make_float2( HF,-HF));
    C[4*2+2] = cmul_mi(C[4*2+2]);                             // W16^4 = -i
    C[4*2+3] = cmul(C[4*2+3], make_float2(-HF,-HF));
    C[4*3+1] = cmul(C[4*3+1], make_float2( S1,-C1));
    C[4*3+2] = cmul(C[4*3+2], make_float2(-HF,-HF));
    C[4*3+3] = cmul(C[4*3+3], make_float2(-C1, S1));          // W16^9
    #pragma unroll
    for (int klo = 0; klo < 4; ++klo) {
        float2 a = C[klo], b = C[4+klo], c = C[8+klo], d = C[12+klo];
        float2 t0 = cadd(a,c), t1 = csub(a,c), t2 = cadd(b,d), t3 = csub(b,d);
        A[klo]    = cadd(t0,t2);
        A[klo+4]  = make_float2(t1.x + t3.y, t1.y - t3.x);
        A[klo+8]  = csub(t0,t2);
        A[klo+12] = make_float2(t1.x - t3.y, t1.y + t3.x);
    }
}

// X[k3] = sum_{j2} h[j2] W4^{j2 k3}
__device__ __forceinline__ void dft4(const float2* h, float2* X) {
    float2 t0 = cadd(h[0],h[2]), t1 = csub(h[0],h[2]);
    float2 t2 = cadd(h[1],h[3]), t3 = csub(h[1],h[3]);
    X[0] = cadd(t0,t2);
    X[1] = make_float2(t1.x + t3.y, t1.y - t3.x);
    X[2] = csub(t0,t2);
    X[3] = make_float2(t1.x - t3.y, t1.y + t3.x);
}

// Hermitian unpack of packed pair at (Z_k, Z_{1024-k}) -> (|A_k|, |B_k|)
__device__ __forceinline__ float2 magpair(float2 Zk, float2 Zm) {
    float ax = Zk.x + Zm.x, ay = Zk.y - Zm.y;
    float bx = Zk.x - Zm.x, by = Zk.y + Zm.y;
    return make_float2(0.5f*sqrtf(ax*ax + ay*ay), 0.5f*sqrtf(bx*bx + by*by));
}

__global__ __launch_bounds__(256, 3)
void stft_mag_kernel(const float* __restrict__ in, float* __restrict__ out) {
    __shared__ float2 fftb[NW][1024];   // 32 KB: per-wave four-step workspace
    __shared__ float  mt[512 * 8];      // 16 KB: mag transpose tile (8 frames)
    const int tid = threadIdx.x, lane = tid & 63, w = tid >> 6;
    const int blk = blockIdx.x, b = blockIdx.y;
    const int p = 4 * blk + w;                 // pair 0..2047 -> frames 2p, 2p+1
    const bool noB = (2 * p + 1) >= NFRAMES;   // only pair 2047
    const float* bi = in + (size_t)b * TLEN;
    float* bo = out + (size_t)b * ((size_t)CUTOFF * NFRAMES);
    float2* buf = fftb[w];

    // ---- load: lane j holds x[64r + j]; z = frameA + i*frameB, frameB[e]=frameA[e+512]
    float v[24];
    const float* src = bi + 1024 * p + lane;
    #pragma unroll
    for (int t = 0; t < 16; ++t) v[t] = src[64 * t];
    #pragma unroll
    for (int t = 16; t < 24; ++t) v[t] = noB ? 0.f : src[64 * t];
    float2 A[16];
    #pragma unroll
    for (int r = 0; r < 16; ++r) A[r] = make_float2(v[r], noB ? 0.f : v[r + 8]);

    // ---- stage A: FFT-16 over r, then T1 twiddle W1024^{lane*k1}
    fft16(A);
    {
        float s, c;
        __sincosf((float)lane * 6.135923151542565e-03f, &s, &c);
        float2 w1 = make_float2(c, -s), t = make_float2(1.f, 0.f);
        #pragma unroll
        for (int k = 1; k < 16; ++k) { t = cmul(t, w1); A[k] = cmul(A[k], t); }
    }
    // transpose 1: addr(k1, j) = 64*k1 + ((j + 4*k1) & 63)
    #pragma unroll
    for (int k = 0; k < 16; ++k)
        buf[64 * k + ((lane + 4 * k) & 63)] = A[k];
    WAVE_SYNC();

    // ---- stage B: lane = (k1 = lane&15, j2 = lane>>4); FFT-16 over j1; T2 W64^{j2*k2}
    const int k1 = lane & 15, j2 = lane >> 4;
    #pragma unroll
    for (int r = 0; r < 16; ++r)
        A[r] = buf[64 * k1 + ((4 * r + j2 + 4 * k1) & 63)];
    fft16(A);
    {
        float s, c;
        __sincosf((float)j2 * 9.817477042468103e-02f, &s, &c);
        float2 w1 = make_float2(c, -s), t = make_float2(1.f, 0.f);
        #pragma unroll
        for (int k = 1; k < 16; ++k) { t = cmul(t, w1); A[k] = cmul(A[k], t); }
    }
    WAVE_SYNC();   // all lanes' stage-B reads drained before in-place overwrite
    // transpose 2: quartet q = k1 + 16*k2 stored at float2 base 4*sigma(q)+j2,
    // sigma(q) = q ^ (q>>4)  => addr = 64*k2 + 4*(k1^k2) + j2 (consecutive per instr)
    #pragma unroll
    for (int k = 0; k < 16; ++k)
        buf[64 * k + 4 * (k1 ^ k) + j2] = A[k];
    WAVE_SYNC();

    // ---- readout: 128 units; lane handles u = 2*lane, 2*lane+1.
    // unit u>0: quartets (u, 256-u) -> bins {u, u+256, 256-u, 512-u} (+mirrors)
    // unit 0  : quartets (0, 128)  -> bins {0, 256, 128, 384} + bin 512 direct
    const int f0 = 2 * w;   // block-local frames: f0 (A), f0+1 (B)
    const float4* q4 = (const float4*)buf;
    auto MTW = [&](int k, int f, float val) {
        mt[8 * k + ((f + (k >> 3)) & 7)] = val;
    };
    #pragma unroll
    for (int vv = 0; vv < 2; ++vv) {
        const int u = 2 * lane + vv;
        if (u == 0) {
            float4 a0 = q4[0], a1 = q4[1];           // sigma(0)=0
            float4 b0 = q4[272], b1 = q4[273];       // sigma(128)=136
            float2 hq[4] = {{a0.x,a0.y},{a0.z,a0.w},{a1.x,a1.y},{a1.z,a1.w}};
            float2 hp[4] = {{b0.x,b0.y},{b0.z,b0.w},{b1.x,b1.y},{b1.z,b1.w}};
            float2 X0[4], X1[4];
            dft4(hq, X0); dft4(hp, X1);
            MTW(0, f0, fabsf(X0[0].x)); MTW(0, f0 + 1, fabsf(X0[0].y));
            float2 m = magpair(X0[1], X0[3]);
            MTW(256, f0, m.x); MTW(256, f0 + 1, m.y);
            bo[(size_t)512 * NFRAMES + 2 * p] = fabsf(X0[2].x);
            if (!noB) bo[(size_t)512 * NFRAMES + 2 * p + 1] = fabsf(X0[2].y);
            m = magpair(X1[0], X1[3]);
            MTW(128, f0, m.x); MTW(128, f0 + 1, m.y);
            m = magpair(X1[1], X1[2]);
            MTW(384, f0, m.x); MTW(384, f0 + 1, m.y);
        } else {
            const int q = u, qp = 256 - u;
            const int sq = q ^ (q >> 4), sp = qp ^ (qp >> 4);
            float4 a0 = q4[2*sq], a1 = q4[2*sq+1], b0 = q4[2*sp], b1 = q4[2*sp+1];
            float2 hq[4] = {{a0.x,a0.y},{a0.z,a0.w},{a1.x,a1.y},{a1.z,a1.w}};
            float2 hp[4] = {{b0.x,b0.y},{b0.z,b0.w},{b1.x,b1.y},{b1.z,b1.w}};
            float2 Xq[4], Xp[4];
            dft4(hq, Xq); dft4(hp, Xp);
            float2 m;
            m = magpair(Xq[0], Xp[3]); MTW(u,       f0, m.x); MTW(u,       f0+1, m.y);
            m = magpair(Xq[1], Xp[2]); MTW(u + 256, f0, m.x); MTW(u + 256, f0+1, m.y);
            m = magpair(Xp[0], Xq[3]); MTW(256 - u, f0, m.x); MTW(256 - u, f0+1, m.y);
            m = magpair(Xp[1], Xq[2]); MTW(512 - u, f0, m.x); MTW(512 - u, f0+1, m.y);
        }
    }
    __syncthreads();

    // ---- flush mag tile: rows c=0..511, 8 frames/row (32B runs)
    #pragma unroll
    for (int i = 0; i < 16; ++i) {
        int L = 256 * i + tid;
        int c = L >> 3, f = L & 7;
        int n = 8 * blk + f;
        if (n < NFRAMES)
            bo[(size_t)c * NFRAMES + n] = mt[8 * c + ((f + (c >> 3)) & 7)];
    }
}

extern "C" void kernel_launch(void* const* d_in, const int* in_sizes, int n_in,
                              void* d_out, int out_size, void* d_ws, size_t ws_size,
                              hipStream_t stream) {
    const float* in = (const float*)d_in[0];   // (16, 2097152) fp32
    // d_in[1] (forward_basis) unused: it is exactly the DFT matrix; computed as FFT here.
    float* out = (float*)d_out;                // (16, 513, 4095) fp32
    dim3 grid(512, NBATCH, 1);                 // 512 * 8 frames >= 4095
    stft_mag_kernel<<<grid, 256, 0, stream>>>(in, out);
}